// Round 2
// baseline (62.807 us; speedup 1.0000x reference)
//
#include <hip/hip_runtime.h>
#include <hip/hip_bf16.h>

// Closed-form reduction:
//   s = A @ x  (A: [5000,20], x: [20])
//   loss = sum_{i,j} (s_i - b_j)^2
//        = N * sum(s^2) - 2 * sum(s) * sum(b) + N * sum(b^2),  N = 5000
//
// Single-block fused kernel (1 dispatch): 1024 threads / 16 waves on one CU.
// Each 20-float row of A is 80 B and 16 B-aligned -> 5 float4 loads per row.
// Double accumulation; wave shuffle + LDS block reduction; thread 0 emits
// the scalar directly to d_out. No workspace, no atomics, deterministic.

#define N_ROWS 5000
#define N_FEAT 20
#define BLKSZ  1024
#define NWAVES (BLKSZ / 64)

__device__ __forceinline__ double wave_reduce_sum(double v) {
    #pragma unroll
    for (int off = 32; off > 0; off >>= 1)
        v += __shfl_down(v, off, 64);
    return v;
}

__global__ __launch_bounds__(BLKSZ) void lsq_fused_kernel(
        const float* __restrict__ A, const float* __restrict__ b,
        const float* __restrict__ x, float* __restrict__ out) {
    // Stage x in registers via LDS broadcast (20 floats).
    __shared__ float xs[N_FEAT];
    if (threadIdx.x < N_FEAT) xs[threadIdx.x] = x[threadIdx.x];
    __syncthreads();

    float x0 = xs[0],  x1 = xs[1],  x2 = xs[2],  x3 = xs[3],  x4 = xs[4];
    float x5 = xs[5],  x6 = xs[6],  x7 = xs[7],  x8 = xs[8],  x9 = xs[9];
    float x10 = xs[10], x11 = xs[11], x12 = xs[12], x13 = xs[13], x14 = xs[14];
    float x15 = xs[15], x16 = xs[16], x17 = xs[17], x18 = xs[18], x19 = xs[19];

    double s1 = 0.0, s2 = 0.0, b1 = 0.0, b2 = 0.0;
    for (int i = threadIdx.x; i < N_ROWS; i += BLKSZ) {
        const float4* __restrict__ row = (const float4*)(A + (long)i * N_FEAT);
        float4 r0 = row[0], r1 = row[1], r2 = row[2], r3 = row[3], r4 = row[4];
        float bv = b[i];

        float s = r0.x * x0  + r0.y * x1  + r0.z * x2  + r0.w * x3
                + r1.x * x4  + r1.y * x5  + r1.z * x6  + r1.w * x7
                + r2.x * x8  + r2.y * x9  + r2.z * x10 + r2.w * x11
                + r3.x * x12 + r3.y * x13 + r3.z * x14 + r3.w * x15
                + r4.x * x16 + r4.y * x17 + r4.z * x18 + r4.w * x19;

        s1 += (double)s;
        s2 += (double)s * (double)s;
        b1 += (double)bv;
        b2 += (double)bv * (double)bv;
    }

    s1 = wave_reduce_sum(s1);
    s2 = wave_reduce_sum(s2);
    b1 = wave_reduce_sum(b1);
    b2 = wave_reduce_sum(b2);

    __shared__ double red[NWAVES][4];
    int lane = threadIdx.x & 63;
    int wave = threadIdx.x >> 6;
    if (lane == 0) {
        red[wave][0] = s1; red[wave][1] = s2;
        red[wave][2] = b1; red[wave][3] = b2;
    }
    __syncthreads();
    if (threadIdx.x == 0) {
        double t0 = 0, t1 = 0, t2 = 0, t3 = 0;
        #pragma unroll
        for (int w = 0; w < NWAVES; ++w) {
            t0 += red[w][0]; t1 += red[w][1];
            t2 += red[w][2]; t3 += red[w][3];
        }
        double n = (double)N_ROWS;
        out[0] = (float)(n * t1 - 2.0 * t0 * t2 + n * t3);
    }
}

extern "C" void kernel_launch(void* const* d_in, const int* in_sizes, int n_in,
                              void* d_out, int out_size, void* d_ws, size_t ws_size,
                              hipStream_t stream) {
    const float* A = (const float*)d_in[0];   // [5000,20]
    const float* b = (const float*)d_in[1];   // [5000]
    const float* x = (const float*)d_in[2];   // [20]
    float* out = (float*)d_out;
    (void)d_ws; (void)ws_size;

    lsq_fused_kernel<<<1, BLKSZ, 0, stream>>>(A, b, x, out);
}